// Round 1
// baseline (833.652 us; speedup 1.0000x reference)
//
#include <hip/hip_runtime.h>
#include <math.h>

// Problem constants (from reference): B=4, N=2048, DIN=DOUT=512, H=8, HD=64
#define CB 4
#define CN 2048
#define CDIN 512
#define CDOUT 512
#define CH 8
#define CHD 64
#define CM (CB * CN)  // 8192 rows of x

// ---------------------------------------------------------------------------
// Fused QKV projection: y[m,o] = sum_k x[m,k] * W[o,k] + b[o]
// Output written head-major: out[b][h][n][hd], hd contiguous.
// 64x64 output tile per block, BK=32, 256 threads, 4x4 micro-tile per thread.
// ---------------------------------------------------------------------------
__global__ __launch_bounds__(256) void proj_kernel(
    const float* __restrict__ x,
    const float* __restrict__ Wq, const float* __restrict__ bq,
    const float* __restrict__ Wk, const float* __restrict__ bk,
    const float* __restrict__ Wv, const float* __restrict__ bv,
    float* __restrict__ Qo, float* __restrict__ Ko, float* __restrict__ Vo)
{
    const float* W; const float* bias; float* out;
    if (blockIdx.z == 0)      { W = Wq; bias = bq; out = Qo; }
    else if (blockIdx.z == 1) { W = Wk; bias = bk; out = Ko; }
    else                      { W = Wv; bias = bv; out = Vo; }

    __shared__ float As[32][64];  // [k][m] (transposed so micro-tile reads are float4)
    __shared__ float Ws[32][64];  // [k][o]

    const int tid = threadIdx.x;
    const int m0 = blockIdx.x * 64;
    const int o0 = blockIdx.y * 64;
    const int ty = tid >> 4;      // 0..15 -> 4 output rows
    const int tx = tid & 15;      // 0..15 -> 4 output cols

    const int r  = tid >> 3;        // 0..31 (row within half-tile)
    const int kk = (tid & 7) * 4;   // 0..28 (k offset, float4)

    float acc[4][4] = {};

    for (int k0 = 0; k0 < CDIN; k0 += 32) {
        #pragma unroll
        for (int half = 0; half < 2; ++half) {
            int row = r + half * 32;
            float4 a = *(const float4*)&x[(size_t)(m0 + row) * CDIN + k0 + kk];
            As[kk + 0][row] = a.x; As[kk + 1][row] = a.y;
            As[kk + 2][row] = a.z; As[kk + 3][row] = a.w;
            float4 w = *(const float4*)&W[(size_t)(o0 + row) * CDIN + k0 + kk];
            Ws[kk + 0][row] = w.x; Ws[kk + 1][row] = w.y;
            Ws[kk + 2][row] = w.z; Ws[kk + 3][row] = w.w;
        }
        __syncthreads();
        #pragma unroll 8
        for (int k = 0; k < 32; ++k) {
            float4 a4 = *(const float4*)&As[k][ty * 4];
            float4 b4 = *(const float4*)&Ws[k][tx * 4];
            const float av[4] = {a4.x, a4.y, a4.z, a4.w};
            const float bw[4] = {b4.x, b4.y, b4.z, b4.w};
            #pragma unroll
            for (int i = 0; i < 4; ++i)
                #pragma unroll
                for (int j = 0; j < 4; ++j)
                    acc[i][j] = fmaf(av[i], bw[j], acc[i][j]);
        }
        __syncthreads();
    }

    // o-tile is 64 wide and 64-aligned -> exactly one head
    const int h = o0 / CHD;
    float bvals[4];
    #pragma unroll
    for (int j = 0; j < 4; ++j) bvals[j] = bias[o0 + tx * 4 + j];

    #pragma unroll
    for (int i = 0; i < 4; ++i) {
        int m = m0 + ty * 4 + i;
        int bb = m / CN, n = m % CN;
        float4 v;
        v.x = acc[i][0] + bvals[0];
        v.y = acc[i][1] + bvals[1];
        v.z = acc[i][2] + bvals[2];
        v.w = acc[i][3] + bvals[3];
        *(float4*)&out[(((size_t)bb * CH + h) * CN + n) * CHD + tx * 4] = v;
    }
}

// ---------------------------------------------------------------------------
// Flash attention + ELU. One block = (b, h, 64 query rows). 256 threads.
// K and V share one LDS buffer (K used for S, then reloaded as V for PV)
// to stay under the 64 KB static-LDS limit.
// Stride 68 (not 64/65): keeps float4 alignment, breaks power-of-2 banks.
// ---------------------------------------------------------------------------
#define LDS_STRIDE 68

__global__ __launch_bounds__(256) void attn_kernel(
    const float* __restrict__ Q, const float* __restrict__ K,
    const float* __restrict__ V, const int* __restrict__ mask,
    float* __restrict__ out)
{
    __shared__ float Qt[64][LDS_STRIDE];   // [d][i]  Q tile transposed
    __shared__ float KV[64][LDS_STRIDE];   // as Kt[d][j] for S, then Vs[j][d] for PV
    __shared__ float Ps[64][LDS_STRIDE];   // [j][i]  P transposed
    __shared__ float m_s[64], l_s[64], alpha_s[64];
    __shared__ float red[64][17];

    const int tid = threadIdx.x;
    const int q0  = blockIdx.x * 64;
    const int bh  = blockIdx.y;            // = b*H + h
    const int b   = bh / CH;
    const int h   = bh % CH;
    const int ty  = tid >> 4, tx = tid & 15;

    const float* Qb = Q + (size_t)bh * CN * CHD;
    const float* Kb = K + (size_t)bh * CN * CHD;
    const float* Vb = V + (size_t)bh * CN * CHD;
    const int*   mb = mask + (size_t)b * CN * CN;

    // Load Q tile transposed: Qt[d][i]
    {
        int i  = tid >> 2;             // 0..63
        int d0 = (tid & 3) * 16;       // 0,16,32,48
        #pragma unroll
        for (int c = 0; c < 4; ++c) {
            float4 q4 = *(const float4*)&Qb[(size_t)(q0 + i) * CHD + d0 + c * 4];
            Qt[d0 + c * 4 + 0][i] = q4.x; Qt[d0 + c * 4 + 1][i] = q4.y;
            Qt[d0 + c * 4 + 2][i] = q4.z; Qt[d0 + c * 4 + 3][i] = q4.w;
        }
    }
    if (tid < 64) { m_s[tid] = -3.0e38f; l_s[tid] = 0.0f; }

    float acc[4][4] = {};
    __syncthreads();

    for (int kt = 0; kt < CN / 64; ++kt) {
        // ---- load K tile transposed into KV: Kt[d][j] ----
        {
            int j  = tid >> 2;
            int d0 = (tid & 3) * 16;
            #pragma unroll
            for (int c = 0; c < 4; ++c) {
                float4 k4 = *(const float4*)&Kb[(size_t)(kt * 64 + j) * CHD + d0 + c * 4];
                KV[d0 + c * 4 + 0][j] = k4.x; KV[d0 + c * 4 + 1][j] = k4.y;
                KV[d0 + c * 4 + 2][j] = k4.z; KV[d0 + c * 4 + 3][j] = k4.w;
            }
        }
        __syncthreads();

        // ---- S = Q K^T for this tile (4x4 per thread) ----
        float s[4][4] = {};
        #pragma unroll 8
        for (int d = 0; d < 64; ++d) {
            float4 a4 = *(const float4*)&Qt[d][ty * 4];
            float4 b4 = *(const float4*)&KV[d][tx * 4];
            const float av[4] = {a4.x, a4.y, a4.z, a4.w};
            const float bw[4] = {b4.x, b4.y, b4.z, b4.w};
            #pragma unroll
            for (int i = 0; i < 4; ++i)
                #pragma unroll
                for (int j = 0; j < 4; ++j)
                    s[i][j] = fmaf(av[i], bw[j], s[i][j]);
        }
        __syncthreads();   // K reads done; KV may be overwritten with V

        // ---- start V load into KV: Vs[j][d] (direct, no transpose) ----
        {
            int j  = tid >> 2;
            int d0 = (tid & 3) * 16;
            #pragma unroll
            for (int c = 0; c < 4; ++c) {
                *(float4*)&KV[j][d0 + c * 4] =
                    *(const float4*)&Vb[(size_t)(kt * 64 + j) * CHD + d0 + c * 4];
            }
        }

        // ---- scale + mask ----
        #pragma unroll
        for (int i = 0; i < 4; ++i) {
            int qg = q0 + ty * 4 + i;
            int4 mv = *(const int4*)&mb[(size_t)qg * CN + kt * 64 + tx * 4];
            s[i][0] = mv.x ? s[i][0] * 0.125f : -1.0e9f;
            s[i][1] = mv.y ? s[i][1] * 0.125f : -1.0e9f;
            s[i][2] = mv.z ? s[i][2] * 0.125f : -1.0e9f;
            s[i][3] = mv.w ? s[i][3] * 0.125f : -1.0e9f;
        }

        // ---- online softmax: row max ----
        #pragma unroll
        for (int i = 0; i < 4; ++i) {
            float rm = fmaxf(fmaxf(s[i][0], s[i][1]), fmaxf(s[i][2], s[i][3]));
            red[ty * 4 + i][tx] = rm;
        }
        __syncthreads();
        if (tid < 64) {
            float rm = red[tid][0];
            #pragma unroll
            for (int t = 1; t < 16; ++t) rm = fmaxf(rm, red[tid][t]);
            float nm = fmaxf(m_s[tid], rm);
            alpha_s[tid] = __expf(m_s[tid] - nm);
            m_s[tid] = nm;
        }
        __syncthreads();

        // ---- P = exp(S - m), store transposed Ps[j][i], row-sum partials ----
        #pragma unroll
        for (int i = 0; i < 4; ++i) {
            float mrow = m_s[ty * 4 + i];
            float rs = 0.0f;
            #pragma unroll
            for (int j = 0; j < 4; ++j) {
                float p = __expf(s[i][j] - mrow);
                Ps[tx * 4 + j][ty * 4 + i] = p;
                rs += p;
            }
            red[ty * 4 + i][tx] = rs;
        }
        __syncthreads();
        if (tid < 64) {
            float rs = 0.0f;
            #pragma unroll
            for (int t = 0; t < 16; ++t) rs += red[tid][t];
            l_s[tid] = l_s[tid] * alpha_s[tid] + rs;
        }
        __syncthreads();   // Ps + V in LDS complete; alpha_s valid

        // ---- rescale accumulator, then O += P V ----
        #pragma unroll
        for (int i = 0; i < 4; ++i) {
            float al = alpha_s[ty * 4 + i];
            #pragma unroll
            for (int j = 0; j < 4; ++j) acc[i][j] *= al;
        }
        #pragma unroll 8
        for (int j = 0; j < 64; ++j) {
            float4 p4 = *(const float4*)&Ps[j][ty * 4];
            float4 v4 = *(const float4*)&KV[j][tx * 4];
            const float pv[4] = {p4.x, p4.y, p4.z, p4.w};
            const float vv[4] = {v4.x, v4.y, v4.z, v4.w};
            #pragma unroll
            for (int i = 0; i < 4; ++i)
                #pragma unroll
                for (int d = 0; d < 4; ++d)
                    acc[i][d] = fmaf(pv[i], vv[d], acc[i][d]);
        }
        __syncthreads();   // PV reads done; next iter may overwrite KV/Ps
    }

    // ---- epilogue: normalize, ELU, store [b][n][h*HD+d] ----
    #pragma unroll
    for (int i = 0; i < 4; ++i) {
        int n = q0 + ty * 4 + i;
        float inv = 1.0f / l_s[ty * 4 + i];
        float vals[4];
        #pragma unroll
        for (int j = 0; j < 4; ++j) {
            float c = acc[i][j] * inv;
            vals[j] = c > 0.0f ? c : expm1f(c);
        }
        float4 o = {vals[0], vals[1], vals[2], vals[3]};
        *(float4*)&out[((size_t)b * CN + n) * CDOUT + h * CHD + tx * 4] = o;
    }
}

extern "C" void kernel_launch(void* const* d_in, const int* in_sizes, int n_in,
                              void* d_out, int out_size, void* d_ws, size_t ws_size,
                              hipStream_t stream) {
    const float* x    = (const float*)d_in[0];
    const float* Wq   = (const float*)d_in[1];
    const float* bq   = (const float*)d_in[2];
    const float* Wk   = (const float*)d_in[3];
    const float* bk   = (const float*)d_in[4];
    const float* Wv   = (const float*)d_in[5];
    const float* bv   = (const float*)d_in[6];
    const int*   mask = (const int*)d_in[7];
    float* out = (float*)d_out;

    // Workspace: Q, K, V in [B][H][N][HD] fp32 (16 MB each, 48 MB total)
    float* Qw = (float*)d_ws;
    float* Kw = Qw + (size_t)CM * CDOUT;
    float* Vw = Kw + (size_t)CM * CDOUT;

    proj_kernel<<<dim3(CM / 64, CDOUT / 64, 3), 256, 0, stream>>>(
        x, Wq, bq, Wk, bk, Wv, bv, Qw, Kw, Vw);
    attn_kernel<<<dim3(CN / 64, CB * CH), 256, 0, stream>>>(
        Qw, Kw, Vw, mask, out);
}

// Round 2
// 355.719 us; speedup vs baseline: 2.3436x; 2.3436x over previous
//
#include <hip/hip_runtime.h>
#include <math.h>
#include <stdint.h>

// B=4, N=2048, DIN=DOUT=512, H=8, HD=64
#define CB 4
#define CN 2048
#define CDIN 512
#define CDOUT 512
#define CH 8
#define CHD 64
#define CM (CB * CN)
#define CBH (CB * CH)

typedef __attribute__((ext_vector_type(8))) short short8;   // 8 bf16 (4 VGPR) MFMA A/B frag
typedef __attribute__((ext_vector_type(4))) short short4v;  // 8-byte LDS/global packet
typedef __attribute__((ext_vector_type(4))) float f32x4;    // MFMA C/D frag

__device__ __forceinline__ uint16_t f2bf(float f) {
    union { float f; uint32_t u; } v{f};
    uint32_t r = v.u + 0x7fffu + ((v.u >> 16) & 1u);  // RNE
    return (uint16_t)(r >> 16);
}
__device__ __forceinline__ float bf2f(uint16_t b) {
    union { uint32_t u; float f; } v{(uint32_t)b << 16};
    return v.f;
}

// ---------------------------------------------------------------------------
// QKV projection, bf16 MFMA with hi/lo split (~fp32 accuracy).
// y[m,o] = sum_k x[m,k] W[o,k] + b[o]
// Emits: Q,K as hi+lo bf16 in [BH][N][HD]; V as bf16 TRANSPOSED [BH][HD][N]
// (so attention's B-fragments for PV are contiguous ds_read_b128).
// Block: 256 thr = 4 waves; tile 64(m) x 64(o); K-chunks of 64.
// ---------------------------------------------------------------------------
__global__ __launch_bounds__(256) void proj_kernel(
    const float* __restrict__ x,
    const float* __restrict__ Wq, const float* __restrict__ bq,
    const float* __restrict__ Wk, const float* __restrict__ bk,
    const float* __restrict__ Wv, const float* __restrict__ bv,
    uint16_t* __restrict__ Qhi, uint16_t* __restrict__ Qlo,
    uint16_t* __restrict__ Khi, uint16_t* __restrict__ Klo,
    uint16_t* __restrict__ Vt)
{
    const int z = blockIdx.z;
    const float* W; const float* bias;
    if (z == 0)      { W = Wq; bias = bq; }
    else if (z == 1) { W = Wk; bias = bk; }
    else             { W = Wv; bias = bv; }

    // stride 72 bf16 = 144 B: 16B-aligned rows, bank offset 4/row -> <=2-way (free)
    __shared__ __attribute__((aligned(16))) uint16_t Xh[64][72], Xl[64][72];
    __shared__ __attribute__((aligned(16))) uint16_t Wh[64][72], Wl[64][72];

    const int tid  = threadIdx.x;
    const int m0   = blockIdx.x * 64;
    const int o0   = blockIdx.y * 64;        // head = blockIdx.y
    const int lane = tid & 63, w = tid >> 6;
    const int il   = lane & 15, quad = lane >> 4;
    const int srow = tid >> 2, sc0 = (tid & 3) * 16;

    f32x4 acc[4] = {};  // 4 o-subtiles of 16

    for (int k0 = 0; k0 < CDIN; k0 += 64) {
        // stage x and W 64x64 fp32 -> hi/lo bf16 in LDS
        const float* xr = &x[(size_t)(m0 + srow) * CDIN + k0 + sc0];
        const float* wr = &W[(size_t)(o0 + srow) * CDIN + k0 + sc0];
        #pragma unroll
        for (int c = 0; c < 4; ++c) {
            float4 v = *(const float4*)(xr + c * 4);
            uint16_t h0 = f2bf(v.x), h1 = f2bf(v.y), h2 = f2bf(v.z), h3 = f2bf(v.w);
            short4v hv = {(short)h0, (short)h1, (short)h2, (short)h3};
            short4v lv = {(short)f2bf(v.x - bf2f(h0)), (short)f2bf(v.y - bf2f(h1)),
                          (short)f2bf(v.z - bf2f(h2)), (short)f2bf(v.w - bf2f(h3))};
            *(short4v*)&Xh[srow][sc0 + c * 4] = hv;
            *(short4v*)&Xl[srow][sc0 + c * 4] = lv;
            float4 u = *(const float4*)(wr + c * 4);
            uint16_t g0 = f2bf(u.x), g1 = f2bf(u.y), g2 = f2bf(u.z), g3 = f2bf(u.w);
            short4v gv = {(short)g0, (short)g1, (short)g2, (short)g3};
            short4v mv = {(short)f2bf(u.x - bf2f(g0)), (short)f2bf(u.y - bf2f(g1)),
                          (short)f2bf(u.z - bf2f(g2)), (short)f2bf(u.w - bf2f(g3))};
            *(short4v*)&Wh[srow][sc0 + c * 4] = gv;
            *(short4v*)&Wl[srow][sc0 + c * 4] = mv;
        }
        __syncthreads();

        #pragma unroll
        for (int dh = 0; dh < 2; ++dh) {
            short8 Axh = *(const short8*)&Xh[w * 16 + il][dh * 32 + quad * 8];
            short8 Axl = *(const short8*)&Xl[w * 16 + il][dh * 32 + quad * 8];
            #pragma unroll
            for (int s = 0; s < 4; ++s) {
                short8 Bwh = *(const short8*)&Wh[s * 16 + il][dh * 32 + quad * 8];
                short8 Bwl = *(const short8*)&Wl[s * 16 + il][dh * 32 + quad * 8];
                acc[s] = __builtin_amdgcn_mfma_f32_16x16x32_bf16(Axh, Bwh, acc[s], 0, 0, 0);
                acc[s] = __builtin_amdgcn_mfma_f32_16x16x32_bf16(Axh, Bwl, acc[s], 0, 0, 0);
                acc[s] = __builtin_amdgcn_mfma_f32_16x16x32_bf16(Axl, Bwh, acc[s], 0, 0, 0);
            }
        }
        __syncthreads();
    }

    // epilogue: +bias, split/store. D layout: col(o)=il, row(m)=quad*4+reg.
    const int b = m0 / CN;
    const int h = o0 >> 6;
    #pragma unroll
    for (int s = 0; s < 4; ++s) {
        const int d = s * 16 + il;
        const float bv_ = bias[o0 + d];
        if (z < 2) {
            #pragma unroll
            for (int r = 0; r < 4; ++r) {
                int n = (m0 + w * 16 + quad * 4 + r) & (CN - 1);
                float y = acc[s][r] + bv_;
                uint16_t hi = f2bf(y);
                uint16_t lo = f2bf(y - bf2f(hi));
                size_t idx = ((size_t)(b * CH + h) * CN + n) * CHD + d;
                if (z == 0) { Qhi[idx] = hi; Qlo[idx] = lo; }
                else        { Khi[idx] = hi; Klo[idx] = lo; }
            }
        } else {
            uint16_t p[4];
            #pragma unroll
            for (int r = 0; r < 4; ++r) p[r] = f2bf(acc[s][r] + bv_);
            int n0 = (m0 + w * 16 + quad * 4) & (CN - 1);
            size_t idx = ((size_t)(b * CH + h) * CHD + d) * CN + n0;
            short4v pv = {(short)p[0], (short)p[1], (short)p[2], (short)p[3]};
            *(short4v*)&Vt[idx] = pv;
        }
    }
}

// ---------------------------------------------------------------------------
// Flash attention on MFMA. Block = (64 q-rows, bh); 4 waves; wave w owns
// q-rows [16w,16w+16). Computes S^T (A=K, B=Q) so each lane holds ONE q-row
// (softmax = per-lane + 2 shfl_xor). P -> wave-private LDS -> A-frags for PV.
// QK^T uses hi/lo split (3 mfma); PV plain bf16.
// ---------------------------------------------------------------------------
__global__ __launch_bounds__(256) void attn_kernel(
    const uint16_t* __restrict__ Qhi, const uint16_t* __restrict__ Qlo,
    const uint16_t* __restrict__ Khi, const uint16_t* __restrict__ Klo,
    const uint16_t* __restrict__ Vt, const int* __restrict__ mask,
    float* __restrict__ out)
{
    __shared__ __attribute__((aligned(16))) uint16_t Ksh[64][72], Ksl[64][72];
    __shared__ __attribute__((aligned(16))) uint16_t Vs[64][72];
    __shared__ __attribute__((aligned(16))) uint16_t Ps[4][16][72];

    const int tid  = threadIdx.x;
    const int q0   = blockIdx.x * 64;
    const int bh   = blockIdx.y;
    const int b    = bh >> 3, h = bh & 7;
    const int lane = tid & 63, w = tid >> 6;
    const int il   = lane & 15, quad = lane >> 4;
    const int srow = tid >> 2, sc0 = (tid & 3) * 16;

    const uint16_t* Qhb = Qhi + (size_t)bh * CN * CHD;
    const uint16_t* Qlb = Qlo + (size_t)bh * CN * CHD;
    const uint16_t* Khb = Khi + (size_t)bh * CN * CHD;
    const uint16_t* Klb = Klo + (size_t)bh * CN * CHD;
    const uint16_t* Vtb = Vt  + (size_t)bh * CHD * CN;
    const int*      mb  = mask + (size_t)b * CN * CN;

    const int qg = q0 + w * 16 + il;  // this lane's q row

    short8 Qh[2], Ql[2];
    #pragma unroll
    for (int dh = 0; dh < 2; ++dh) {
        Qh[dh] = *(const short8*)&Qhb[(size_t)qg * CHD + dh * 32 + quad * 8];
        Ql[dh] = *(const short8*)&Qlb[(size_t)qg * CHD + dh * 32 + quad * 8];
    }

    float m_i = -INFINITY, l_i = 0.f;
    f32x4 oacc[4] = {};

    for (int kt = 0; kt < CN / 64; ++kt) {
        // stage K hi/lo [j][d] and V^T [d][j] tiles
        {
            const uint4* kh = (const uint4*)&Khb[(size_t)(kt * 64 + srow) * CHD + sc0];
            const uint4* kl = (const uint4*)&Klb[(size_t)(kt * 64 + srow) * CHD + sc0];
            const uint4* vv = (const uint4*)&Vtb[(size_t)srow * CN + kt * 64 + sc0];
            uint4 a0 = kh[0], a1 = kh[1], b0 = kl[0], b1 = kl[1], c0 = vv[0], c1 = vv[1];
            *(uint4*)&Ksh[srow][sc0]     = a0; *(uint4*)&Ksh[srow][sc0 + 8] = a1;
            *(uint4*)&Ksl[srow][sc0]     = b0; *(uint4*)&Ksl[srow][sc0 + 8] = b1;
            *(uint4*)&Vs[srow][sc0]      = c0; *(uint4*)&Vs[srow][sc0 + 8]  = c1;
        }
        __syncthreads();

        // S^T[j][i]: A=K (rows j), B=Q (rows i). 3-term hi/lo split.
        f32x4 st[4] = {};
        #pragma unroll
        for (int s = 0; s < 4; ++s) {
            #pragma unroll
            for (int dh = 0; dh < 2; ++dh) {
                short8 Ah = *(const short8*)&Ksh[s * 16 + il][dh * 32 + quad * 8];
                short8 Al = *(const short8*)&Ksl[s * 16 + il][dh * 32 + quad * 8];
                st[s] = __builtin_amdgcn_mfma_f32_16x16x32_bf16(Ah, Qh[dh], st[s], 0, 0, 0);
                st[s] = __builtin_amdgcn_mfma_f32_16x16x32_bf16(Ah, Ql[dh], st[s], 0, 0, 0);
                st[s] = __builtin_amdgcn_mfma_f32_16x16x32_bf16(Al, Qh[dh], st[s], 0, 0, 0);
            }
        }

        // mask + scale; lane holds q-row qg, keys j = s*16 + quad*4 + r
        float rowmax = -INFINITY;
        #pragma unroll
        for (int s = 0; s < 4; ++s) {
            int4 mv = *(const int4*)&mb[(size_t)qg * CN + kt * 64 + s * 16 + quad * 4];
            st[s][0] = mv.x ? st[s][0] * 0.125f : -1e9f;
            st[s][1] = mv.y ? st[s][1] * 0.125f : -1e9f;
            st[s][2] = mv.z ? st[s][2] * 0.125f : -1e9f;
            st[s][3] = mv.w ? st[s][3] * 0.125f : -1e9f;
            rowmax = fmaxf(rowmax,
                     fmaxf(fmaxf(st[s][0], st[s][1]), fmaxf(st[s][2], st[s][3])));
        }
        rowmax = fmaxf(rowmax, __shfl_xor(rowmax, 16));
        rowmax = fmaxf(rowmax, __shfl_xor(rowmax, 32));
        const float m_new = fmaxf(m_i, rowmax);
        const float alpha = __expf(m_i - m_new);
        m_i = m_new;

        float psum = 0.f;
        #pragma unroll
        for (int s = 0; s < 4; ++s) {
            uint16_t pb[4];
            #pragma unroll
            for (int r = 0; r < 4; ++r) {
                float p = __expf(st[s][r] - m_new);
                pb[r] = f2bf(p);
                psum += bf2f(pb[r]);   // sum the rounded values (consistent with PV)
            }
            short4v pv4 = {(short)pb[0], (short)pb[1], (short)pb[2], (short)pb[3]};
            *(short4v*)&Ps[w][il][s * 16 + quad * 4] = pv4;
        }
        psum += __shfl_xor(psum, 16);
        psum += __shfl_xor(psum, 32);
        l_i = l_i * alpha + psum;

        // rescale O acc (rows i = quad*4+r; alpha lives on lane i)
        float arow[4];
        #pragma unroll
        for (int r = 0; r < 4; ++r) arow[r] = __shfl(alpha, quad * 4 + r);
        #pragma unroll
        for (int s = 0; s < 4; ++s) {
            #pragma unroll
            for (int r = 0; r < 4; ++r) oacc[s][r] *= arow[r];
        }
        __syncthreads();  // P visible (wave-private, but be conservative)

        // O += P V : A = P[i][j] from LDS, B = V^T[d][j] from LDS
        short8 Pa[2];
        #pragma unroll
        for (int jh = 0; jh < 2; ++jh)
            Pa[jh] = *(const short8*)&Ps[w][il][jh * 32 + quad * 8];
        #pragma unroll
        for (int s = 0; s < 4; ++s) {
            #pragma unroll
            for (int jh = 0; jh < 2; ++jh) {
                short8 Bv = *(const short8*)&Vs[s * 16 + il][jh * 32 + quad * 8];
                oacc[s] = __builtin_amdgcn_mfma_f32_16x16x32_bf16(Pa[jh], Bv, oacc[s], 0, 0, 0);
            }
        }
        __syncthreads();  // staging for next tile overwrites Ksh/Ksl/Vs
    }

    // epilogue: /l, ELU, store [b][n][h*64+d]
    float lrow[4];
    #pragma unroll
    for (int r = 0; r < 4; ++r) lrow[r] = __shfl(l_i, quad * 4 + r);
    #pragma unroll
    for (int s = 0; s < 4; ++s) {
        const int d = h * CHD + s * 16 + il;
        #pragma unroll
        for (int r = 0; r < 4; ++r) {
            int n = q0 + w * 16 + quad * 4 + r;
            float c = oacc[s][r] / lrow[r];
            float e = c > 0.f ? c : expm1f(c);
            out[((size_t)b * CN + n) * CDOUT + d] = e;
        }
    }
}

extern "C" void kernel_launch(void* const* d_in, const int* in_sizes, int n_in,
                              void* d_out, int out_size, void* d_ws, size_t ws_size,
                              hipStream_t stream) {
    const float* x    = (const float*)d_in[0];
    const float* Wq   = (const float*)d_in[1];
    const float* bq   = (const float*)d_in[2];
    const float* Wk   = (const float*)d_in[3];
    const float* bk   = (const float*)d_in[4];
    const float* Wv   = (const float*)d_in[5];
    const float* bv   = (const float*)d_in[6];
    const int*   mask = (const int*)d_in[7];
    float* out = (float*)d_out;

    const size_t tsz = (size_t)CBH * CN * CHD;  // 4.19M elems, 8 MB bf16 each
    uint16_t* Qhi = (uint16_t*)d_ws;
    uint16_t* Qlo = Qhi + tsz;
    uint16_t* Khi = Qlo + tsz;
    uint16_t* Klo = Khi + tsz;
    uint16_t* Vt  = Klo + tsz;

    proj_kernel<<<dim3(CM / 64, CDOUT / 64, 3), 256, 0, stream>>>(
        x, Wq, bq, Wk, bk, Wv, bv, Qhi, Qlo, Khi, Klo, Vt);
    attn_kernel<<<dim3(CN / 64, CBH), 256, 0, stream>>>(
        Qhi, Qlo, Khi, Klo, Vt, mask, out);
}

// Round 3
// 240.300 us; speedup vs baseline: 3.4692x; 1.4803x over previous
//
#include <hip/hip_runtime.h>
#include <math.h>
#include <stdint.h>

// B=4, N=2048, DIN=DOUT=512, H=8, HD=64
#define CB 4
#define CN 2048
#define CDIN 512
#define CDOUT 512
#define CH 8
#define CHD 64
#define CM (CB * CN)
#define CBH (CB * CH)

typedef _Float16 f16x8 __attribute__((ext_vector_type(8)));  // MFMA A/B frag (4 VGPR)
typedef _Float16 f16x4 __attribute__((ext_vector_type(4)));  // 8-byte packet
typedef float    f32x4 __attribute__((ext_vector_type(4)));  // MFMA C/D frag

// log2(e)/8 : folded into Q at projection time so softmax runs in exp2 domain
#define QSCALE 0.1803368801111204f

// ---------------------------------------------------------------------------
// One-shot fp32 -> fp16 conversion of x, Wq, Wk, Wv (removes per-tile
// conversion VALU from the projection kernel; x was being re-converted 24x).
// ---------------------------------------------------------------------------
__global__ __launch_bounds__(256) void cvt_kernel(
    const float* __restrict__ s0, _Float16* __restrict__ d0, int n0,
    const float* __restrict__ s1, _Float16* __restrict__ d1, int n1,
    const float* __restrict__ s2, _Float16* __restrict__ d2, int n2,
    const float* __restrict__ s3, _Float16* __restrict__ d3, int n3)
{
    const float* s; _Float16* d; int n;
    if (blockIdx.y == 0)      { s = s0; d = d0; n = n0; }
    else if (blockIdx.y == 1) { s = s1; d = d1; n = n1; }
    else if (blockIdx.y == 2) { s = s2; d = d2; n = n2; }
    else                      { s = s3; d = d3; n = n3; }
    int i = (blockIdx.x * 256 + threadIdx.x) * 8;
    const int stride = gridDim.x * 256 * 8;
    for (; i < n; i += stride) {
        float4 a = *(const float4*)&s[i];
        float4 b = *(const float4*)&s[i + 4];
        f16x8 h = {(_Float16)a.x, (_Float16)a.y, (_Float16)a.z, (_Float16)a.w,
                   (_Float16)b.x, (_Float16)b.y, (_Float16)b.z, (_Float16)b.w};
        *(f16x8*)&d[i] = h;
    }
}

// ---------------------------------------------------------------------------
// QKV projection, single fp16 MFMA. Tile 128(m) x 64(o), BK=64, 256 thr.
// Q gets QSCALE folded in. V stored transposed [bh][d][n] for attn's PV B-frags.
// ---------------------------------------------------------------------------
__global__ __launch_bounds__(256) void proj_kernel(
    const _Float16* __restrict__ xh,
    const _Float16* __restrict__ Wqh, const float* __restrict__ bq,
    const _Float16* __restrict__ Wkh, const float* __restrict__ bk,
    const _Float16* __restrict__ Wvh, const float* __restrict__ bv,
    _Float16* __restrict__ Qf, _Float16* __restrict__ Kf, _Float16* __restrict__ Vt)
{
    const int z = blockIdx.z;
    const _Float16* W; const float* bias;
    if (z == 0)      { W = Wqh; bias = bq; }
    else if (z == 1) { W = Wkh; bias = bk; }
    else             { W = Wvh; bias = bv; }

    // stride 72 fp16 = 144 B: 16B-aligned rows, 4-bank row stagger
    __shared__ _Float16 Xs[128][72];
    __shared__ _Float16 Ws[64][72];

    const int tid  = threadIdx.x;
    const int m0   = blockIdx.x * 128;
    const int h    = blockIdx.y;           // o0 = h*64, one head per o-tile
    const int o0   = h * 64;
    const int lane = tid & 63, w = tid >> 6;
    const int il   = lane & 15, quad = lane >> 4;

    f32x4 acc[2][4] = {};

    for (int k0 = 0; k0 < CDIN; k0 += 64) {
        #pragma unroll
        for (int i = 0; i < 4; ++i) {
            int seg = tid + i * 256;            // 1024 segs: 128 rows x 8
            int row = seg >> 3, kc = (seg & 7) * 8;
            *(f16x8*)&Xs[row][kc] = *(const f16x8*)&xh[(size_t)(m0 + row) * CDIN + k0 + kc];
        }
        #pragma unroll
        for (int i = 0; i < 2; ++i) {
            int seg = tid + i * 256;            // 512 segs: 64 rows x 8
            int row = seg >> 3, kc = (seg & 7) * 8;
            *(f16x8*)&Ws[row][kc] = *(const f16x8*)&W[(size_t)(o0 + row) * CDIN + k0 + kc];
        }
        __syncthreads();
        #pragma unroll
        for (int dh = 0; dh < 2; ++dh) {
            f16x8 A0 = *(const f16x8*)&Xs[w * 32 + il][dh * 32 + quad * 8];
            f16x8 A1 = *(const f16x8*)&Xs[w * 32 + 16 + il][dh * 32 + quad * 8];
            #pragma unroll
            for (int s = 0; s < 4; ++s) {
                f16x8 Bv = *(const f16x8*)&Ws[s * 16 + il][dh * 32 + quad * 8];
                acc[0][s] = __builtin_amdgcn_mfma_f32_16x16x32_f16(A0, Bv, acc[0][s], 0, 0, 0);
                acc[1][s] = __builtin_amdgcn_mfma_f32_16x16x32_f16(A1, Bv, acc[1][s], 0, 0, 0);
            }
        }
        __syncthreads();
    }

    // D layout: col(o)=il, row(m)=quad*4+reg
    const int b  = m0 / CN;                 // 128-row tiles never straddle a batch
    const int bh = b * CH + h;
    if (z < 2) {
        _Float16* dst = (z == 0) ? Qf : Kf;
        const float sc = (z == 0) ? QSCALE : 1.0f;
        #pragma unroll
        for (int s = 0; s < 4; ++s) {
            const int d = s * 16 + il;
            const float bval = bias[o0 + d];
            #pragma unroll
            for (int mi = 0; mi < 2; ++mi) {
                #pragma unroll
                for (int r = 0; r < 4; ++r) {
                    int n = (m0 + w * 32 + mi * 16 + quad * 4 + r) & (CN - 1);
                    dst[((size_t)bh * CN + n) * CHD + d] =
                        (_Float16)((acc[mi][s][r] + bval) * sc);
                }
            }
        }
    } else {
        #pragma unroll
        for (int s = 0; s < 4; ++s) {
            const int d = s * 16 + il;
            const float bval = bias[o0 + d];
            #pragma unroll
            for (int mi = 0; mi < 2; ++mi) {
                int n0 = (m0 + w * 32 + mi * 16 + quad * 4) & (CN - 1);
                f16x4 pv = {(_Float16)(acc[mi][s][0] + bval),
                            (_Float16)(acc[mi][s][1] + bval),
                            (_Float16)(acc[mi][s][2] + bval),
                            (_Float16)(acc[mi][s][3] + bval)};
                *(f16x4*)&Vt[((size_t)bh * CHD + d) * CN + n0] = pv;
            }
        }
    }
}

// ---------------------------------------------------------------------------
// Flash attention, single fp16 MFMA. Block = (64 q-rows, bh), 4 waves; wave w
// owns q-rows [16w,16w+16). S^T trick (A=K, B=Q) -> per-lane softmax.
// Q pre-scaled by log2(e)/8 -> softmax in exp2 domain.
// Ps is wave-private: no barrier between P-store and PV (2 barriers/tile).
// LDS 27.6 KB -> 4 blocks/CU (all 1024 blocks resident).
// ---------------------------------------------------------------------------
__global__ __launch_bounds__(256) void attn_kernel(
    const _Float16* __restrict__ Qf, const _Float16* __restrict__ Kf,
    const _Float16* __restrict__ Vt, const int* __restrict__ mask,
    float* __restrict__ out)
{
    __shared__ _Float16 Ks[64][72];
    __shared__ _Float16 Vs[64][72];
    __shared__ _Float16 Ps[4][16][72];

    const int tid  = threadIdx.x;
    const int q0   = blockIdx.x * 64;
    const int bh   = blockIdx.y;
    const int b    = bh >> 3, h = bh & 7;
    const int lane = tid & 63, w = tid >> 6;
    const int il   = lane & 15, quad = lane >> 4;
    const int srow = tid >> 2, sc0 = (tid & 3) * 16;

    const _Float16* Qb = Qf + (size_t)bh * CN * CHD;
    const _Float16* Kb = Kf + (size_t)bh * CN * CHD;
    const _Float16* Vb = Vt + (size_t)bh * CHD * CN;
    const int*      mb = mask + (size_t)b * CN * CN;

    const int qg = q0 + w * 16 + il;       // this lane's q row
    f16x8 Qa[2];
    Qa[0] = *(const f16x8*)&Qb[(size_t)qg * CHD + quad * 8];
    Qa[1] = *(const f16x8*)&Qb[(size_t)qg * CHD + 32 + quad * 8];

    float m_i = -INFINITY, l_i = 0.f;
    f32x4 oacc[4] = {};

    for (int kt = 0; kt < CN / 64; ++kt) {
        // stage K [j][d] and V^T [d][j] (each thread: 32 B of each, coalesced)
        {
            const uint4* kp = (const uint4*)&Kb[(size_t)(kt * 64 + srow) * CHD + sc0];
            const uint4* vp = (const uint4*)&Vb[(size_t)srow * CN + kt * 64 + sc0];
            uint4 k0v = kp[0], k1v = kp[1], v0v = vp[0], v1v = vp[1];
            *(uint4*)&Ks[srow][sc0]     = k0v; *(uint4*)&Ks[srow][sc0 + 8] = k1v;
            *(uint4*)&Vs[srow][sc0]     = v0v; *(uint4*)&Vs[srow][sc0 + 8] = v1v;
        }
        __syncthreads();

        // S^T[j][i] in exp2 domain (Q pre-scaled): 8 MFMA
        f32x4 st[4] = {};
        #pragma unroll
        for (int s = 0; s < 4; ++s) {
            f16x8 A0 = *(const f16x8*)&Ks[s * 16 + il][quad * 8];
            f16x8 A1 = *(const f16x8*)&Ks[s * 16 + il][32 + quad * 8];
            st[s] = __builtin_amdgcn_mfma_f32_16x16x32_f16(A0, Qa[0], st[s], 0, 0, 0);
            st[s] = __builtin_amdgcn_mfma_f32_16x16x32_f16(A1, Qa[1], st[s], 0, 0, 0);
        }

        // mask; keys j = s*16 + quad*4 + r, all for this lane's q-row qg
        float rowmax = -INFINITY;
        #pragma unroll
        for (int s = 0; s < 4; ++s) {
            int4 mv = *(const int4*)&mb[(size_t)qg * CN + kt * 64 + s * 16 + quad * 4];
            st[s][0] = mv.x ? st[s][0] : -1e9f;
            st[s][1] = mv.y ? st[s][1] : -1e9f;
            st[s][2] = mv.z ? st[s][2] : -1e9f;
            st[s][3] = mv.w ? st[s][3] : -1e9f;
            rowmax = fmaxf(rowmax,
                     fmaxf(fmaxf(st[s][0], st[s][1]), fmaxf(st[s][2], st[s][3])));
        }
        rowmax = fmaxf(rowmax, __shfl_xor(rowmax, 16));
        rowmax = fmaxf(rowmax, __shfl_xor(rowmax, 32));
        const float m_new = fmaxf(m_i, rowmax);
        const float alpha = exp2f(m_i - m_new);
        m_i = m_new;

        float psum = 0.f;
        #pragma unroll
        for (int s = 0; s < 4; ++s) {
            f16x4 pv;
            #pragma unroll
            for (int r = 0; r < 4; ++r) {
                float p = exp2f(st[s][r] - m_new);
                _Float16 ph = (_Float16)p;
                pv[r] = ph;
                psum += (float)ph;     // sum rounded values, consistent with PV
            }
            *(f16x4*)&Ps[w][il][s * 16 + quad * 4] = pv;
        }
        psum += __shfl_xor(psum, 16);
        psum += __shfl_xor(psum, 32);
        l_i = l_i * alpha + psum;

        // rescale O (rows i = quad*4+r; alpha lives on lane with il = i)
        float arow[4];
        #pragma unroll
        for (int r = 0; r < 4; ++r) arow[r] = __shfl(alpha, quad * 4 + r);
        #pragma unroll
        for (int s = 0; s < 4; ++s)
            #pragma unroll
            for (int r = 0; r < 4; ++r) oacc[s][r] *= arow[r];

        // O += P V (Ps wave-private: lgkmcnt wait only, no barrier)
        f16x8 Pa0 = *(const f16x8*)&Ps[w][il][quad * 8];
        f16x8 Pa1 = *(const f16x8*)&Ps[w][il][32 + quad * 8];
        #pragma unroll
        for (int s = 0; s < 4; ++s) {
            f16x8 B0 = *(const f16x8*)&Vs[s * 16 + il][quad * 8];
            f16x8 B1 = *(const f16x8*)&Vs[s * 16 + il][32 + quad * 8];
            oacc[s] = __builtin_amdgcn_mfma_f32_16x16x32_f16(Pa0, B0, oacc[s], 0, 0, 0);
            oacc[s] = __builtin_amdgcn_mfma_f32_16x16x32_f16(Pa1, B1, oacc[s], 0, 0, 0);
        }
        __syncthreads();   // protect Ks/Vs before next tile's staging
    }

    // epilogue: /l, ELU, store [b][n][h*64+d]
    float lrow[4];
    #pragma unroll
    for (int r = 0; r < 4; ++r) lrow[r] = __shfl(l_i, quad * 4 + r);
    #pragma unroll
    for (int s = 0; s < 4; ++s) {
        const int d = h * CHD + s * 16 + il;
        #pragma unroll
        for (int r = 0; r < 4; ++r) {
            int n = q0 + w * 16 + quad * 4 + r;
            float c = oacc[s][r] / lrow[r];
            out[((size_t)b * CN + n) * CDOUT + d] = c > 0.f ? c : expm1f(c);
        }
    }
}

extern "C" void kernel_launch(void* const* d_in, const int* in_sizes, int n_in,
                              void* d_out, int out_size, void* d_ws, size_t ws_size,
                              hipStream_t stream) {
    const float* x    = (const float*)d_in[0];
    const float* Wq   = (const float*)d_in[1];
    const float* bq   = (const float*)d_in[2];
    const float* Wk   = (const float*)d_in[3];
    const float* bk   = (const float*)d_in[4];
    const float* Wv   = (const float*)d_in[5];
    const float* bv   = (const float*)d_in[6];
    const int*   mask = (const int*)d_in[7];
    float* out = (float*)d_out;

    const size_t nx = (size_t)CM * CDIN;       // 4,194,304
    const size_t nw = (size_t)CDOUT * CDIN;    // 262,144
    const size_t nt = (size_t)CBH * CN * CHD;  // 4,194,304
    _Float16* xh  = (_Float16*)d_ws;
    _Float16* wqh = xh + nx;
    _Float16* wkh = wqh + nw;
    _Float16* wvh = wkh + nw;
    _Float16* Qf  = wvh + nw;
    _Float16* Kf  = Qf + nt;
    _Float16* Vt  = Kf + nt;   // total ~35 MB

    cvt_kernel<<<dim3(2048, 4), 256, 0, stream>>>(
        x, xh, (int)nx, Wq, wqh, (int)nw, Wk, wkh, (int)nw, Wv, wvh, (int)nw);
    proj_kernel<<<dim3(CM / 128, CH, 3), 256, 0, stream>>>(
        xh, wqh, bq, wkh, bk, wvh, bv, Qf, Kf, Vt);
    attn_kernel<<<dim3(CN / 64, CBH), 256, 0, stream>>>(
        Qf, Kf, Vt, mask, out);
}